// Round 1
// baseline (578.965 us; speedup 1.0000x reference)
//
#include <hip/hip_runtime.h>

// GraphConvNet: x:[8,2048,32] f32, A0/A1/A2:[8,2048,2048] f32 row-normalized,
// W:[64,224], b/gamma/beta:[64].
// out[n,w,l] of nconv = sum_v A[n,v,w] * x[n,v,l]  (einsum 'nvl,nvw->nwl')
// feat = concat([x, x1_0, x2_0, x1_1, x2_1, x1_2, x2_2])  (224 ch)
// h = feat @ W^T + b ; BN over (n,v) per channel; out f32 [8,2048,64]

#define V    2048
#define NB   8
#define CIN  32
#define KC   64
#define COUT 64
#define CTOT 224

// ---------------------------------------------------------------------------
// nconv: one adjacency hop. Block: 256 thr, tile 64 w x 32 l, K loop over v.
// Thread microtile: 2 w x 4 l. Double-buffered LDS, issue-early/write-late.
// ---------------------------------------------------------------------------
__global__ __launch_bounds__(256) void nconv_kernel(
    const float* __restrict__ A, const float* __restrict__ Xin,
    float* __restrict__ Xout) {
  __shared__ float Alds[2][KC][64];   // [v][w]  32 KB
  __shared__ float Xlds[2][KC][CIN];  // [v][l]  16 KB
  const int n  = blockIdx.y;
  const int w0 = blockIdx.x * 64;
  const int t  = threadIdx.x;
  const int wg = t & 31;   // w-group: w = w0 + wg*2 + {0,1}
  const int lg = t >> 5;   // l-group: l = lg*4 .. +3

  const float* __restrict__ Ab = A + (size_t)n * V * V + w0;
  const float* __restrict__ Xb = Xin + (size_t)n * V * CIN;

  float4 ra[4];
  float4 rx[2];
  float acc[2][4] = {{0.f, 0.f, 0.f, 0.f}, {0.f, 0.f, 0.f, 0.f}};

  auto load_chunk = [&](int v0) {
#pragma unroll
    for (int s = 0; s < 4; ++s) {           // A chunk: 64x64 f32
      int fl = t + s * 256;
      int r = fl >> 4, c4 = fl & 15;
      ra[s] = *(const float4*)(Ab + (size_t)(v0 + r) * V + c4 * 4);
    }
#pragma unroll
    for (int s = 0; s < 2; ++s) {           // X chunk: 64x32 f32
      int fl = t + s * 256;
      int r = fl >> 3, c4 = fl & 7;
      rx[s] = *(const float4*)(Xb + (v0 + r) * CIN + c4 * 4);
    }
  };
  auto write_chunk = [&](int b) {
#pragma unroll
    for (int s = 0; s < 4; ++s) {
      int fl = t + s * 256;
      int r = fl >> 4, c4 = fl & 15;
      *(float4*)&Alds[b][r][c4 * 4] = ra[s];
    }
#pragma unroll
    for (int s = 0; s < 2; ++s) {
      int fl = t + s * 256;
      int r = fl >> 3, c4 = fl & 7;
      *(float4*)&Xlds[b][r][c4 * 4] = rx[s];
    }
  };

  load_chunk(0);
  write_chunk(0);
  __syncthreads();

  int buf = 0;
  for (int v0 = 0; v0 < V; v0 += KC) {
    const bool more = (v0 + KC) < V;
    if (more) load_chunk(v0 + KC);          // issue global loads early
#pragma unroll 8
    for (int r = 0; r < KC; ++r) {
      const float2 av = *(const float2*)&Alds[buf][r][wg * 2];
      const float4 xv = *(const float4*)&Xlds[buf][r][lg * 4];
      acc[0][0] += av.x * xv.x; acc[0][1] += av.x * xv.y;
      acc[0][2] += av.x * xv.z; acc[0][3] += av.x * xv.w;
      acc[1][0] += av.y * xv.x; acc[1][1] += av.y * xv.y;
      acc[1][2] += av.y * xv.z; acc[1][3] += av.y * xv.w;
    }
    if (more) write_chunk(buf ^ 1);         // write-late into other buffer
    __syncthreads();
    buf ^= 1;
  }

  float* __restrict__ Ob =
      Xout + ((size_t)n * V + w0 + wg * 2) * CIN + lg * 4;
  *(float4*)Ob = make_float4(acc[0][0], acc[0][1], acc[0][2], acc[0][3]);
  *(float4*)(Ob + CIN) =
      make_float4(acc[1][0], acc[1][1], acc[1][2], acc[1][3]);
}

// ---------------------------------------------------------------------------
// conv 1x1 + bias + BN batch-stats partials.
// Block: 256 thr, 64 rows x 64 outch. LDS: W(57KB) + feat(57KB), XOR-swizzled
// rows so the 4-row x128-read fragments are ~2-way bank-aliased (free).
// ---------------------------------------------------------------------------
__global__ __launch_bounds__(256) void conv_bn_stats_kernel(
    const float* __restrict__ W, const float* __restrict__ bias,
    const float* __restrict__ p0, const float* __restrict__ p1,
    const float* __restrict__ p2, const float* __restrict__ p3,
    const float* __restrict__ p4, const float* __restrict__ p5,
    const float* __restrict__ p6, float* __restrict__ hout,
    float* __restrict__ stats) {
  __shared__ float Wl[COUT * CTOT];  // [o][c]  swizzled
  __shared__ float Fl[64 * CTOT];    // [r][c]  swizzled
  const int t = threadIdx.x;
  const int R0 = blockIdx.x * 64;    // flat (n*V + v) row base

  // stage W
#pragma unroll
  for (int s = 0; s < 14; ++s) {
    int fl = t + s * 256;            // 3584 float4
    int o = fl / 56, c4 = fl % 56;
    float4 wv = *(const float4*)(W + o * CTOT + c4 * 4);
    int c = c4 * 4;
    int csw = c ^ (((o >> 2) & 7) << 2);
    *(float4*)&Wl[o * CTOT + csw] = wv;
  }
  // stage 7 feature parts
  const float* parts[7] = {p0, p1, p2, p3, p4, p5, p6};
#pragma unroll
  for (int p = 0; p < 7; ++p) {
    const float* __restrict__ src = parts[p] + (size_t)R0 * CIN;
#pragma unroll
    for (int s = 0; s < 2; ++s) {
      int fl = t + s * 256;          // 512 float4 per part
      int r = fl >> 3, c4 = fl & 7;
      float4 v = *(const float4*)(src + r * CIN + c4 * 4);
      int c = p * 32 + c4 * 4;
      int csw = c ^ (((r >> 2) & 7) << 2);
      *(float4*)&Fl[r * CTOT + csw] = v;
    }
  }
  __syncthreads();

  const int rg = t & 15, og = t >> 4;
  const int r0 = rg * 4, o0 = og * 4;
  float acc[4][4];
#pragma unroll
  for (int i = 0; i < 4; ++i)
#pragma unroll
    for (int j = 0; j < 4; ++j) acc[i][j] = bias[o0 + j];

  const int fsw = (rg & 7) << 2;
  const int wsw = (og & 7) << 2;
  for (int cc = 0; cc < CTOT; cc += 4) {
    float4 f[4], w[4];
#pragma unroll
    for (int i = 0; i < 4; ++i)
      f[i] = *(const float4*)&Fl[(r0 + i) * CTOT + (cc ^ fsw)];
#pragma unroll
    for (int j = 0; j < 4; ++j)
      w[j] = *(const float4*)&Wl[(o0 + j) * CTOT + (cc ^ wsw)];
#pragma unroll
    for (int i = 0; i < 4; ++i)
#pragma unroll
      for (int j = 0; j < 4; ++j)
        acc[i][j] += f[i].x * w[j].x + f[i].y * w[j].y + f[i].z * w[j].z +
                     f[i].w * w[j].w;
  }

  // write h (pre-BN) to output buffer
#pragma unroll
  for (int i = 0; i < 4; ++i) {
    *(float4*)(hout + (size_t)(R0 + r0 + i) * COUT + o0) =
        make_float4(acc[i][0], acc[i][1], acc[i][2], acc[i][3]);
  }

  // block-level partial sums for BN stats
  __syncthreads();
  float* red = Fl;  // reuse: [2][64][16]
#pragma unroll
  for (int j = 0; j < 4; ++j) {
    float s = acc[0][j] + acc[1][j] + acc[2][j] + acc[3][j];
    float q = acc[0][j] * acc[0][j] + acc[1][j] * acc[1][j] +
              acc[2][j] * acc[2][j] + acc[3][j] * acc[3][j];
    red[(o0 + j) * 16 + rg] = s;
    red[1024 + (o0 + j) * 16 + rg] = q;
  }
  __syncthreads();
  if (t < 128) {
    int o = t & 63, which = t >> 6;
    const float* b = red + which * 1024 + o * 16;
    float v = 0.f;
#pragma unroll
    for (int k = 0; k < 16; ++k) v += b[k];
    atomicAdd(stats + which * COUT + o, v);
  }
}

// ---------------------------------------------------------------------------
// BN apply (in-place on hout)
// ---------------------------------------------------------------------------
__global__ __launch_bounds__(256) void bn_apply_kernel(
    float* __restrict__ hout, const float* __restrict__ stats,
    const float* __restrict__ gamma, const float* __restrict__ beta) {
  const int i4 = blockIdx.x * 256 + threadIdx.x;  // 262144 float4s
  const int oi = i4 & 15;                          // 4 consecutive o
  float4 h = ((const float4*)hout)[i4];
  const float4 s = ((const float4*)stats)[oi];
  const float4 q = ((const float4*)(stats + COUT))[oi];
  const float4 g = ((const float4*)gamma)[oi];
  const float4 bb = ((const float4*)beta)[oi];
  const float inv = 1.f / 16384.f;
  float m, vv, rs;
  m = s.x * inv; vv = q.x * inv - m * m; rs = rsqrtf(vv + 1e-5f);
  h.x = (h.x - m) * rs * g.x + bb.x;
  m = s.y * inv; vv = q.y * inv - m * m; rs = rsqrtf(vv + 1e-5f);
  h.y = (h.y - m) * rs * g.y + bb.y;
  m = s.z * inv; vv = q.z * inv - m * m; rs = rsqrtf(vv + 1e-5f);
  h.z = (h.z - m) * rs * g.z + bb.z;
  m = s.w * inv; vv = q.w * inv - m * m; rs = rsqrtf(vv + 1e-5f);
  h.w = (h.w - m) * rs * g.w + bb.w;
  ((float4*)hout)[i4] = h;
}

// ---------------------------------------------------------------------------
extern "C" void kernel_launch(void* const* d_in, const int* in_sizes, int n_in,
                              void* d_out, int out_size, void* d_ws,
                              size_t ws_size, hipStream_t stream) {
  const float* x     = (const float*)d_in[0];
  const float* A0    = (const float*)d_in[1];
  const float* A1    = (const float*)d_in[2];
  const float* A2    = (const float*)d_in[3];
  const float* W     = (const float*)d_in[4];
  const float* b     = (const float*)d_in[5];
  const float* gamma = (const float*)d_in[6];
  const float* beta  = (const float*)d_in[7];
  float* out = (float*)d_out;

  char* ws = (char*)d_ws;
  float* stats = (float*)ws;                       // 2*64 floats
  const size_t BUF = (size_t)NB * V * CIN;         // 524288 floats (2 MB)
  float* x1_0 = (float*)(ws + 4096);
  float* x2_0 = x1_0 + BUF;
  float* x1_1 = x2_0 + BUF;
  float* x2_1 = x1_1 + BUF;
  float* x1_2 = x2_1 + BUF;
  float* x2_2 = x1_2 + BUF;

  hipMemsetAsync(stats, 0, 2 * COUT * sizeof(float), stream);

  dim3 g(V / 64, NB), blk(256);
  // per-A pairs so hop2 re-reads A from Infinity Cache (128 MB < 256 MB L3)
  nconv_kernel<<<g, blk, 0, stream>>>(A0, x, x1_0);
  nconv_kernel<<<g, blk, 0, stream>>>(A0, x1_0, x2_0);
  nconv_kernel<<<g, blk, 0, stream>>>(A1, x, x1_1);
  nconv_kernel<<<g, blk, 0, stream>>>(A1, x1_1, x2_1);
  nconv_kernel<<<g, blk, 0, stream>>>(A2, x, x1_2);
  nconv_kernel<<<g, blk, 0, stream>>>(A2, x1_2, x2_2);

  conv_bn_stats_kernel<<<dim3(256), blk, 0, stream>>>(
      W, b, x, x1_0, x2_0, x1_1, x2_1, x1_2, x2_2, out, stats);
  bn_apply_kernel<<<dim3(1024), blk, 0, stream>>>(out, stats, gamma, beta);
}

// Round 2
// 341.449 us; speedup vs baseline: 1.6956x; 1.6956x over previous
//
#include <hip/hip_runtime.h>
#include <hip/hip_bf16.h>

// GraphConvNet: x:[8,2048,32] f32, A0/A1/A2:[8,2048,2048] f32 row-normalized,
// W:[64,224], b/gamma/beta:[64].
// nconv: out[n,w,l] = sum_v A[n,v,w] * x[n,v,l]
// feat = concat([x, x1_0, x2_0, x1_1, x2_1, x1_2, x2_2])  (224 ch)
// h = feat @ W^T + b ; BN over (n,v) per channel; out f32 [8,2048,64]

#define V    2048
#define NB   8
#define CIN  32
#define COUT 64
#define CTOT 224

typedef __attribute__((ext_vector_type(8))) short bf16x8;
typedef __attribute__((ext_vector_type(16))) float f32x16;

static __device__ __forceinline__ short f2bf(float f) {
  __hip_bfloat16 h = __float2bfloat16(f);  // RNE; compiler emits v_cvt_pk
  return *reinterpret_cast<short*>(&h);
}

// ---------------------------------------------------------------------------
// nconv via MFMA 32x32x16 bf16.
// Per block: one 32-wide w-strip of one n; 4 warps split K (512 v each).
// Warp computes C^T[l=32][w=32] partial; LDS reduce; coalesced f32 store.
// A-operand = X^T (m=l, k=v), B-operand = Adj (k=v, n=w).
// k-slot map (shared by both operands): v = v0 + g + 2*j  (g=lane>>5, j=0..7)
// -> each load instr j touches 2 consecutive Adj rows x 32 w = 2x128B lines.
// ---------------------------------------------------------------------------
__global__ __launch_bounds__(256) void nconv_mfma_kernel(
    const float* __restrict__ Adj, const float* __restrict__ Xin,
    float* __restrict__ Xout) {
  __shared__ float Lred[4][32][33];  // +1 pad: conflict-light epilogue

  const int bid = blockIdx.x;        // 512 blocks
  const int n   = bid >> 6;          // 8 n
  const int ws  = (bid & 63) * 32;   // w-strip base
  const int t   = threadIdx.x;
  const int q   = t >> 6;            // warp id = K quarter
  const int lane = t & 63;
  const int g   = lane >> 5;         // k-group
  const int mn  = lane & 31;         // m for A-op (l), n for B-op (w)

  // lane base pointers (row v0 = q*512 + g folded in)
  const float* __restrict__ Ap =
      Adj + (size_t)n * V * V + (size_t)(q * 512 + g) * V + ws + mn;
  const float* __restrict__ Xp =
      Xin + (size_t)n * V * CIN + (size_t)(q * 512 + g) * CIN + mn;

  f32x16 acc;
#pragma unroll
  for (int r = 0; r < 16; ++r) acc[r] = 0.f;

#pragma unroll 4
  for (int kk = 0; kk < 32; ++kk) {  // 32 k-steps of 16 v
    float av[8], xv[8];
#pragma unroll
    for (int j = 0; j < 8; ++j) {
      av[j] = Ap[(size_t)(2 * j) * V];   // Adj[v0+g+2j][ws+mn]
      xv[j] = Xp[(2 * j) * CIN];         // X  [v0+g+2j][mn]
    }
    bf16x8 af, bfr;
#pragma unroll
    for (int j = 0; j < 8; ++j) {
      af[j]  = f2bf(xv[j]);   // A-operand: X^T[m=l][k]
      bfr[j] = f2bf(av[j]);   // B-operand: Adj[k][n=w]
    }
    acc = __builtin_amdgcn_mfma_f32_32x32x16_bf16(af, bfr, acc, 0, 0, 0);
    Ap += 16 * V;
    Xp += 16 * CIN;
  }

  // write partial C^T[l][w] to LDS:  row l = (r&3)+8*(r>>2)+4*g, col w = mn
#pragma unroll
  for (int r = 0; r < 16; ++r) {
    Lred[q][(r & 3) + 8 * (r >> 2) + 4 * g][mn] = acc[r];
  }
  __syncthreads();

  // reduce 4 warps + store: thread t -> w = t>>3, l = (t&7)*4 + i
  const int w  = t >> 3;
  const int l4 = t & 7;
  float4 o;
  float* op = &o.x;
#pragma unroll
  for (int i = 0; i < 4; ++i) {
    op[i] = Lred[0][l4 * 4 + i][w] + Lred[1][l4 * 4 + i][w] +
            Lred[2][l4 * 4 + i][w] + Lred[3][l4 * 4 + i][w];
  }
  *(float4*)(Xout + ((size_t)n * V + ws + w) * CIN + l4 * 4) = o;
}

// ---------------------------------------------------------------------------
// conv 1x1 + bias + BN batch-stats partials (unchanged, passing).
// ---------------------------------------------------------------------------
__global__ __launch_bounds__(256) void conv_bn_stats_kernel(
    const float* __restrict__ W, const float* __restrict__ bias,
    const float* __restrict__ p0, const float* __restrict__ p1,
    const float* __restrict__ p2, const float* __restrict__ p3,
    const float* __restrict__ p4, const float* __restrict__ p5,
    const float* __restrict__ p6, float* __restrict__ hout,
    float* __restrict__ stats) {
  __shared__ float Wl[COUT * CTOT];
  __shared__ float Fl[64 * CTOT];
  const int t = threadIdx.x;
  const int R0 = blockIdx.x * 64;

#pragma unroll
  for (int s = 0; s < 14; ++s) {
    int fl = t + s * 256;
    int o = fl / 56, c4 = fl % 56;
    float4 wv = *(const float4*)(W + o * CTOT + c4 * 4);
    int c = c4 * 4;
    int csw = c ^ (((o >> 2) & 7) << 2);
    *(float4*)&Wl[o * CTOT + csw] = wv;
  }
  const float* parts[7] = {p0, p1, p2, p3, p4, p5, p6};
#pragma unroll
  for (int p = 0; p < 7; ++p) {
    const float* __restrict__ src = parts[p] + (size_t)R0 * CIN;
#pragma unroll
    for (int s = 0; s < 2; ++s) {
      int fl = t + s * 256;
      int r = fl >> 3, c4 = fl & 7;
      float4 v = *(const float4*)(src + r * CIN + c4 * 4);
      int c = p * 32 + c4 * 4;
      int csw = c ^ (((r >> 2) & 7) << 2);
      *(float4*)&Fl[r * CTOT + csw] = v;
    }
  }
  __syncthreads();

  const int rg = t & 15, og = t >> 4;
  const int r0 = rg * 4, o0 = og * 4;
  float acc[4][4];
#pragma unroll
  for (int i = 0; i < 4; ++i)
#pragma unroll
    for (int j = 0; j < 4; ++j) acc[i][j] = bias[o0 + j];

  const int fsw = (rg & 7) << 2;
  const int wsw = (og & 7) << 2;
  for (int cc = 0; cc < CTOT; cc += 4) {
    float4 f[4], w[4];
#pragma unroll
    for (int i = 0; i < 4; ++i)
      f[i] = *(const float4*)&Fl[(r0 + i) * CTOT + (cc ^ fsw)];
#pragma unroll
    for (int j = 0; j < 4; ++j)
      w[j] = *(const float4*)&Wl[(o0 + j) * CTOT + (cc ^ wsw)];
#pragma unroll
    for (int i = 0; i < 4; ++i)
#pragma unroll
      for (int j = 0; j < 4; ++j)
        acc[i][j] += f[i].x * w[j].x + f[i].y * w[j].y + f[i].z * w[j].z +
                     f[i].w * w[j].w;
  }

#pragma unroll
  for (int i = 0; i < 4; ++i) {
    *(float4*)(hout + (size_t)(R0 + r0 + i) * COUT + o0) =
        make_float4(acc[i][0], acc[i][1], acc[i][2], acc[i][3]);
  }

  __syncthreads();
  float* red = Fl;
#pragma unroll
  for (int j = 0; j < 4; ++j) {
    float s = acc[0][j] + acc[1][j] + acc[2][j] + acc[3][j];
    float qq = acc[0][j] * acc[0][j] + acc[1][j] * acc[1][j] +
               acc[2][j] * acc[2][j] + acc[3][j] * acc[3][j];
    red[(o0 + j) * 16 + rg] = s;
    red[1024 + (o0 + j) * 16 + rg] = qq;
  }
  __syncthreads();
  if (t < 128) {
    int o = t & 63, which = t >> 6;
    const float* b = red + which * 1024 + o * 16;
    float v = 0.f;
#pragma unroll
    for (int k = 0; k < 16; ++k) v += b[k];
    atomicAdd(stats + which * COUT + o, v);
  }
}

// ---------------------------------------------------------------------------
__global__ __launch_bounds__(256) void bn_apply_kernel(
    float* __restrict__ hout, const float* __restrict__ stats,
    const float* __restrict__ gamma, const float* __restrict__ beta) {
  const int i4 = blockIdx.x * 256 + threadIdx.x;
  const int oi = i4 & 15;
  float4 h = ((const float4*)hout)[i4];
  const float4 s = ((const float4*)stats)[oi];
  const float4 q = ((const float4*)(stats + COUT))[oi];
  const float4 g = ((const float4*)gamma)[oi];
  const float4 bb = ((const float4*)beta)[oi];
  const float inv = 1.f / 16384.f;
  float m, vv, rs;
  m = s.x * inv; vv = q.x * inv - m * m; rs = rsqrtf(vv + 1e-5f);
  h.x = (h.x - m) * rs * g.x + bb.x;
  m = s.y * inv; vv = q.y * inv - m * m; rs = rsqrtf(vv + 1e-5f);
  h.y = (h.y - m) * rs * g.y + bb.y;
  m = s.z * inv; vv = q.z * inv - m * m; rs = rsqrtf(vv + 1e-5f);
  h.z = (h.z - m) * rs * g.z + bb.z;
  m = s.w * inv; vv = q.w * inv - m * m; rs = rsqrtf(vv + 1e-5f);
  h.w = (h.w - m) * rs * g.w + bb.w;
  ((float4*)hout)[i4] = h;
}

// ---------------------------------------------------------------------------
extern "C" void kernel_launch(void* const* d_in, const int* in_sizes, int n_in,
                              void* d_out, int out_size, void* d_ws,
                              size_t ws_size, hipStream_t stream) {
  const float* x     = (const float*)d_in[0];
  const float* A0    = (const float*)d_in[1];
  const float* A1    = (const float*)d_in[2];
  const float* A2    = (const float*)d_in[3];
  const float* W     = (const float*)d_in[4];
  const float* b     = (const float*)d_in[5];
  const float* gamma = (const float*)d_in[6];
  const float* beta  = (const float*)d_in[7];
  float* out = (float*)d_out;

  char* ws = (char*)d_ws;
  float* stats = (float*)ws;
  const size_t BUF = (size_t)NB * V * CIN;  // 524288 floats
  float* x1_0 = (float*)(ws + 4096);
  float* x2_0 = x1_0 + BUF;
  float* x1_1 = x2_0 + BUF;
  float* x2_1 = x1_1 + BUF;
  float* x1_2 = x2_1 + BUF;
  float* x2_2 = x1_2 + BUF;

  hipMemsetAsync(stats, 0, 2 * COUT * sizeof(float), stream);

  dim3 g(512), blk(256);
  // per-A pairs so hop2 re-reads A from Infinity Cache (128 MB < 256 MB L3)
  nconv_mfma_kernel<<<g, blk, 0, stream>>>(A0, x, x1_0);
  nconv_mfma_kernel<<<g, blk, 0, stream>>>(A0, x1_0, x2_0);
  nconv_mfma_kernel<<<g, blk, 0, stream>>>(A1, x, x1_1);
  nconv_mfma_kernel<<<g, blk, 0, stream>>>(A1, x1_1, x2_1);
  nconv_mfma_kernel<<<g, blk, 0, stream>>>(A2, x, x1_2);
  nconv_mfma_kernel<<<g, blk, 0, stream>>>(A2, x1_2, x2_2);

  conv_bn_stats_kernel<<<dim3(256), blk, 0, stream>>>(
      W, b, x, x1_0, x2_0, x1_1, x2_1, x1_2, x2_2, out, stats);
  bn_apply_kernel<<<dim3(1024), blk, 0, stream>>>(out, stats, gamma, beta);
}

// Round 3
// 204.823 us; speedup vs baseline: 2.8267x; 1.6670x over previous
//
#include <hip/hip_runtime.h>
#include <hip/hip_bf16.h>

// GraphConvNet: x:[8,2048,32] f32, A0/A1/A2:[8,2048,2048] f32 row-normalized,
// W:[64,224], b/gamma/beta:[64].
// nconv: out[n,w,l] = sum_v A[n,v,w] * x[n,v,l]
// feat = concat([x, x1_0, x2_0, x1_1, x2_1, x1_2, x2_2])  (224 ch)
// h = feat @ W^T + b ; BN over (n,v) per channel; out f32 [8,2048,64]

#define V    2048
#define NB   8
#define CIN  32
#define COUT 64
#define CTOT 224

typedef __attribute__((ext_vector_type(8))) short bf16x8;
typedef __attribute__((ext_vector_type(16))) float f32x16;

static __device__ __forceinline__ short f2bf(float f) {
  __hip_bfloat16 h = __float2bfloat16(f);  // RNE
  return *reinterpret_cast<short*>(&h);
}

static __device__ __forceinline__ void gll16(const float* g, float* l) {
  // async global->LDS, 16B/lane; LDS dst = wave-uniform base + lane*16
  __builtin_amdgcn_global_load_lds(
      (const __attribute__((address_space(1))) void*)g,
      (__attribute__((address_space(3))) void*)l, 16, 0, 0);
}

// ---------------------------------------------------------------------------
// nconv via MFMA 32x32x16 bf16, async-LDS pipelined, barrier-free main loop.
// Block: 4 waves, each owns a K-quarter (512 v) of one (n, 32-w strip).
// Per wave: 4-ring of LDS chunks {A[16][32], X[16][32]} f32; prefetch dist 3;
// counted vmcnt(12) before consuming oldest chunk. No __syncthreads until
// the cross-wave reduce epilogue.
// k-slot map (same bijection both operands => correct): v = v0 + 8g + j.
// ---------------------------------------------------------------------------
__global__ __launch_bounds__(256) void nconv_mfma_kernel(
    const float* __restrict__ Adj, const float* __restrict__ Xin,
    float* __restrict__ Xout) {
  __shared__ float S[4][4][2][16][32];  // [wave][ring][A|X][v][c] = 64 KB

  const int bid  = blockIdx.x;    // 512 blocks
  const int n    = bid >> 6;
  const int ws   = (bid & 63) * 32;
  const int t    = threadIdx.x;
  const int q    = t >> 6;        // wave id = K quarter
  const int lane = t & 63;
  const int g    = lane >> 5;
  const int mn   = lane & 31;     // m (=l) for A-op, n (=w) for B-op

  const float* Abase = Adj + (size_t)n * V * V + (size_t)q * 512 * V + ws;
  const float* Xbase = Xin + (size_t)n * V * CIN + q * 512 * CIN;
  // per-lane staging source addresses
  const float* Asrc = Abase + (size_t)(lane >> 3) * V + (lane & 7) * 4;
  const float* Xsrc = Xbase + lane * 4;

  auto stage = [&](int c) {                 // stage chunk c into ring c&3
    const int r = c & 3;
    const float* a = Asrc + (size_t)c * 16 * V;
    const float* x = Xsrc + c * 16 * CIN;
    gll16(a,         &S[q][r][0][0][0]);    // A rows 0..7   (lane>>3, (lane&7)*4)
    gll16(a + 8 * V, &S[q][r][0][8][0]);    // A rows 8..15
    gll16(x,         &S[q][r][1][0][0]);    // X rows 0..7   (contiguous 1KB)
    gll16(x + 256,   &S[q][r][1][8][0]);    // X rows 8..15
  };

  f32x16 acc;
#pragma unroll
  for (int r = 0; r < 16; ++r) acc[r] = 0.f;

  auto compute = [&](int r) {
    float a8[8], x8[8];
#pragma unroll
    for (int j = 0; j < 8; ++j) {
      a8[j] = S[q][r][0][8 * g + j][mn];    // Adj[v][w] -> B operand
      x8[j] = S[q][r][1][8 * g + j][mn];    // X[v][l]   -> A operand (X^T)
    }
    bf16x8 aop, bop;
#pragma unroll
    for (int j = 0; j < 8; ++j) {
      aop[j] = f2bf(x8[j]);
      bop[j] = f2bf(a8[j]);
    }
    acc = __builtin_amdgcn_mfma_f32_32x32x16_bf16(aop, bop, acc, 0, 0, 0);
  };

  stage(0);
  stage(1);
  stage(2);
#pragma unroll 1
  for (int kk = 0; kk < 29; ++kk) {         // 32 chunks of 16 v total
    stage(kk + 3);
    asm volatile("s_waitcnt vmcnt(12)" ::: "memory");  // oldest chunk resident
    __builtin_amdgcn_sched_barrier(0);
    compute(kk & 3);
  }
  asm volatile("s_waitcnt vmcnt(8)" ::: "memory");
  __builtin_amdgcn_sched_barrier(0);
  compute(29 & 3);
  asm volatile("s_waitcnt vmcnt(4)" ::: "memory");
  __builtin_amdgcn_sched_barrier(0);
  compute(30 & 3);
  asm volatile("s_waitcnt vmcnt(0)" ::: "memory");
  __builtin_amdgcn_sched_barrier(0);
  compute(31 & 3);

  // ---- cross-wave K reduce (overlay staging LDS; only barriers here) ----
  __syncthreads();
  float(*Lred)[32][33] = reinterpret_cast<float(*)[32][33]>(&S[0][0][0][0][0]);
#pragma unroll
  for (int r = 0; r < 16; ++r) {
    // C^T[l][w]: row l = (r&3)+8*(r>>2)+4*g, col w = mn
    Lred[q][(r & 3) + 8 * (r >> 2) + 4 * g][mn] = acc[r];
  }
  __syncthreads();
  const int w  = t >> 3;
  const int l4 = t & 7;
  float4 o;
  float* op = &o.x;
#pragma unroll
  for (int i = 0; i < 4; ++i) {
    op[i] = Lred[0][l4 * 4 + i][w] + Lred[1][l4 * 4 + i][w] +
            Lred[2][l4 * 4 + i][w] + Lred[3][l4 * 4 + i][w];
  }
  *(float4*)(Xout + ((size_t)n * V + ws + w) * CIN + l4 * 4) = o;
}

// ---------------------------------------------------------------------------
// conv 1x1 + bias + BN batch-stats partials (unchanged, passing).
// ---------------------------------------------------------------------------
__global__ __launch_bounds__(256) void conv_bn_stats_kernel(
    const float* __restrict__ W, const float* __restrict__ bias,
    const float* __restrict__ p0, const float* __restrict__ p1,
    const float* __restrict__ p2, const float* __restrict__ p3,
    const float* __restrict__ p4, const float* __restrict__ p5,
    const float* __restrict__ p6, float* __restrict__ hout,
    float* __restrict__ stats) {
  __shared__ float Wl[COUT * CTOT];
  __shared__ float Fl[64 * CTOT];
  const int t = threadIdx.x;
  const int R0 = blockIdx.x * 64;

#pragma unroll
  for (int s = 0; s < 14; ++s) {
    int fl = t + s * 256;
    int o = fl / 56, c4 = fl % 56;
    float4 wv = *(const float4*)(W + o * CTOT + c4 * 4);
    int c = c4 * 4;
    int csw = c ^ (((o >> 2) & 7) << 2);
    *(float4*)&Wl[o * CTOT + csw] = wv;
  }
  const float* parts[7] = {p0, p1, p2, p3, p4, p5, p6};
#pragma unroll
  for (int p = 0; p < 7; ++p) {
    const float* __restrict__ src = parts[p] + (size_t)R0 * CIN;
#pragma unroll
    for (int s = 0; s < 2; ++s) {
      int fl = t + s * 256;
      int r = fl >> 3, c4 = fl & 7;
      float4 v = *(const float4*)(src + r * CIN + c4 * 4);
      int c = p * 32 + c4 * 4;
      int csw = c ^ (((r >> 2) & 7) << 2);
      *(float4*)&Fl[r * CTOT + csw] = v;
    }
  }
  __syncthreads();

  const int rg = t & 15, og = t >> 4;
  const int r0 = rg * 4, o0 = og * 4;
  float acc[4][4];
#pragma unroll
  for (int i = 0; i < 4; ++i)
#pragma unroll
    for (int j = 0; j < 4; ++j) acc[i][j] = bias[o0 + j];

  const int fsw = (rg & 7) << 2;
  const int wsw = (og & 7) << 2;
  for (int cc = 0; cc < CTOT; cc += 4) {
    float4 f[4], w[4];
#pragma unroll
    for (int i = 0; i < 4; ++i)
      f[i] = *(const float4*)&Fl[(r0 + i) * CTOT + (cc ^ fsw)];
#pragma unroll
    for (int j = 0; j < 4; ++j)
      w[j] = *(const float4*)&Wl[(o0 + j) * CTOT + (cc ^ wsw)];
#pragma unroll
    for (int i = 0; i < 4; ++i)
#pragma unroll
      for (int j = 0; j < 4; ++j)
        acc[i][j] += f[i].x * w[j].x + f[i].y * w[j].y + f[i].z * w[j].z +
                     f[i].w * w[j].w;
  }

#pragma unroll
  for (int i = 0; i < 4; ++i) {
    *(float4*)(hout + (size_t)(R0 + r0 + i) * COUT + o0) =
        make_float4(acc[i][0], acc[i][1], acc[i][2], acc[i][3]);
  }

  __syncthreads();
  float* red = Fl;
#pragma unroll
  for (int j = 0; j < 4; ++j) {
    float s = acc[0][j] + acc[1][j] + acc[2][j] + acc[3][j];
    float qq = acc[0][j] * acc[0][j] + acc[1][j] * acc[1][j] +
               acc[2][j] * acc[2][j] + acc[3][j] * acc[3][j];
    red[(o0 + j) * 16 + rg] = s;
    red[1024 + (o0 + j) * 16 + rg] = qq;
  }
  __syncthreads();
  if (t < 128) {
    int o = t & 63, which = t >> 6;
    const float* b = red + which * 1024 + o * 16;
    float v = 0.f;
#pragma unroll
    for (int k = 0; k < 16; ++k) v += b[k];
    atomicAdd(stats + which * COUT + o, v);
  }
}

// ---------------------------------------------------------------------------
__global__ __launch_bounds__(256) void bn_apply_kernel(
    float* __restrict__ hout, const float* __restrict__ stats,
    const float* __restrict__ gamma, const float* __restrict__ beta) {
  const int i4 = blockIdx.x * 256 + threadIdx.x;
  const int oi = i4 & 15;
  float4 h = ((const float4*)hout)[i4];
  const float4 s = ((const float4*)stats)[oi];
  const float4 q = ((const float4*)(stats + COUT))[oi];
  const float4 g = ((const float4*)gamma)[oi];
  const float4 bb = ((const float4*)beta)[oi];
  const float inv = 1.f / 16384.f;
  float m, vv, rs;
  m = s.x * inv; vv = q.x * inv - m * m; rs = rsqrtf(vv + 1e-5f);
  h.x = (h.x - m) * rs * g.x + bb.x;
  m = s.y * inv; vv = q.y * inv - m * m; rs = rsqrtf(vv + 1e-5f);
  h.y = (h.y - m) * rs * g.y + bb.y;
  m = s.z * inv; vv = q.z * inv - m * m; rs = rsqrtf(vv + 1e-5f);
  h.z = (h.z - m) * rs * g.z + bb.z;
  m = s.w * inv; vv = q.w * inv - m * m; rs = rsqrtf(vv + 1e-5f);
  h.w = (h.w - m) * rs * g.w + bb.w;
  ((float4*)hout)[i4] = h;
}

// ---------------------------------------------------------------------------
extern "C" void kernel_launch(void* const* d_in, const int* in_sizes, int n_in,
                              void* d_out, int out_size, void* d_ws,
                              size_t ws_size, hipStream_t stream) {
  const float* x     = (const float*)d_in[0];
  const float* A0    = (const float*)d_in[1];
  const float* A1    = (const float*)d_in[2];
  const float* A2    = (const float*)d_in[3];
  const float* W     = (const float*)d_in[4];
  const float* b     = (const float*)d_in[5];
  const float* gamma = (const float*)d_in[6];
  const float* beta  = (const float*)d_in[7];
  float* out = (float*)d_out;

  char* ws = (char*)d_ws;
  float* stats = (float*)ws;
  const size_t BUF = (size_t)NB * V * CIN;  // 524288 floats
  float* x1_0 = (float*)(ws + 4096);
  float* x2_0 = x1_0 + BUF;
  float* x1_1 = x2_0 + BUF;
  float* x2_1 = x1_1 + BUF;
  float* x1_2 = x2_1 + BUF;
  float* x2_2 = x1_2 + BUF;

  hipMemsetAsync(stats, 0, 2 * COUT * sizeof(float), stream);

  dim3 g(512), blk(256);
  // per-A pairs so hop2 re-reads A from Infinity Cache (128 MB < 256 MB L3)
  nconv_mfma_kernel<<<g, blk, 0, stream>>>(A0, x, x1_0);
  nconv_mfma_kernel<<<g, blk, 0, stream>>>(A0, x1_0, x2_0);
  nconv_mfma_kernel<<<g, blk, 0, stream>>>(A1, x, x1_1);
  nconv_mfma_kernel<<<g, blk, 0, stream>>>(A1, x1_1, x2_1);
  nconv_mfma_kernel<<<g, blk, 0, stream>>>(A2, x, x1_2);
  nconv_mfma_kernel<<<g, blk, 0, stream>>>(A2, x1_2, x2_2);

  conv_bn_stats_kernel<<<dim3(256), blk, 0, stream>>>(
      W, b, x, x1_0, x2_0, x1_1, x2_1, x1_2, x2_2, out, stats);
  bn_apply_kernel<<<dim3(1024), blk, 0, stream>>>(out, stats, gamma, beta);
}